// Round 8
// baseline (318.155 us; speedup 1.0000x reference)
//
#include <hip/hip_runtime.h>
#include <math.h>

// Problem constants (match reference)
#define BB 64
#define QQ 64
#define LLEN 4096
#define NE 32

// ---------------------------------------------------------------------------
// Kernel A: per-row (b,q) argmax (first-max tie-break) and logsumexp over
// L=4096 for start_pred (rows 0..4095) and end_pred (rows 4096..8191).
// ---------------------------------------------------------------------------
__global__ __launch_bounds__(256) void rowstat_kernel(
    const float* __restrict__ sp, const float* __restrict__ ep,
    int* __restrict__ amax, float* __restrict__ lse)
{
    int rid = blockIdx.x;                 // 0..8191
    const float* base = (rid < BB * QQ) ? (sp + (size_t)rid * LLEN)
                                        : (ep + (size_t)(rid - BB * QQ) * LLEN);
    int t = threadIdx.x;
    const float4* b4 = (const float4*)base;
    float4 v[4];
#pragma unroll
    for (int k = 0; k < 4; k++) v[k] = b4[t + k * 256];

    float bm = -INFINITY; int bi = 0x7fffffff;
#pragma unroll
    for (int k = 0; k < 4; k++) {
        float a[4] = { v[k].x, v[k].y, v[k].z, v[k].w };
        int base_i = (t + k * 256) * 4;
#pragma unroll
        for (int c = 0; c < 4; c++) {
            int idx = base_i + c;
            if (a[c] > bm || (a[c] == bm && idx < bi)) { bm = a[c]; bi = idx; }
        }
    }
#pragma unroll
    for (int off = 32; off >= 1; off >>= 1) {
        float om = __shfl_xor(bm, off);
        int   oi = __shfl_xor(bi, off);
        if (om > bm || (om == bm && oi < bi)) { bm = om; bi = oi; }
    }
    __shared__ float smax[4]; __shared__ int sidx[4];
    int wave = t >> 6, lane = t & 63;
    if (lane == 0) { smax[wave] = bm; sidx[wave] = bi; }
    __syncthreads();
    float fm = smax[0]; int fi = sidx[0];
#pragma unroll
    for (int w = 1; w < 4; w++) {
        float om = smax[w]; int oi = sidx[w];
        if (om > fm || (om == fm && oi < fi)) { fm = om; fi = oi; }
    }

    float s = 0.f;
#pragma unroll
    for (int k = 0; k < 4; k++) {
        float a[4] = { v[k].x, v[k].y, v[k].z, v[k].w };
#pragma unroll
        for (int c = 0; c < 4; c++) s += __expf(a[c] - fm);
    }
#pragma unroll
    for (int off = 32; off >= 1; off >>= 1) s += __shfl_xor(s, off);
    __shared__ float ssum[4];
    if (lane == 0) ssum[wave] = s;
    __syncthreads();
    if (t == 0) {
        float tot = ssum[0] + ssum[1] + ssum[2] + ssum[3];
        amax[rid] = fi;
        lse[rid]  = fm + logf(tot);
    }
}

// ---------------------------------------------------------------------------
// Cross-lane helpers
// ---------------------------------------------------------------------------
// wave64 u32 min via DPP (row_shr 1/2/4/8, row_bcast15, row_bcast31);
// full-wave min lands in lane 63. Invalid lanes keep identity 0xFFFFFFFF.
__device__ __forceinline__ unsigned int wave_min_u32(unsigned int x) {
    int xi = (int)x;
#define DPP_MIN_STEP(ctrl)                                                     \
    {                                                                          \
        int yi = __builtin_amdgcn_update_dpp(-1, xi, ctrl, 0xf, 0xf, false);   \
        unsigned int a = (unsigned int)xi, bq = (unsigned int)yi;              \
        xi = (int)(a < bq ? a : bq);                                           \
    }
    DPP_MIN_STEP(0x111)  // row_shr:1
    DPP_MIN_STEP(0x112)  // row_shr:2
    DPP_MIN_STEP(0x114)  // row_shr:4
    DPP_MIN_STEP(0x118)  // row_shr:8
    DPP_MIN_STEP(0x142)  // row_bcast:15
    DPP_MIN_STEP(0x143)  // row_bcast:31
#undef DPP_MIN_STEP
    return (unsigned int)__builtin_amdgcn_readlane(xi, 63);
}

// ---------------------------------------------------------------------------
// Kernel C: cost build (f32, bit-matching JAX f32 ops) into LDS; Hungarian
// (JV) in f64, operation-for-operation replica of the numpy reference (full
// row loop — REQUIRED: optimum non-unique, output path-dependent).
// R7 structure: per scan-iteration the argmin reduce is SPLIT —
//   keyhi = min(transform(minv_dec), transform(cur)) per lane (monotone
//   transform commutes with min), so reduceA over transform(minv_dec)
//   overlaps the in-flight ds_read for cur; reduceB runs after arrival;
//   mhi = min(redA, redB); ballot+ffs first-index tie-break; exact lo-phase
//   for full ties. u[] is mirrored in LDS (written once per run: rows enter
//   the tree with their PRE-RUN u, so mid-run staleness is never observed),
//   prefetched alongside the cost element. One block = one sample = 1 wave.
// ---------------------------------------------------------------------------
__global__ __launch_bounds__(64) void match_kernel(
    const float* __restrict__ start_pred, const float* __restrict__ end_pred,
    const float* __restrict__ tag_pred,
    const int* __restrict__ s_label, const int* __restrict__ e_label,
    const int* __restrict__ t_label,
    const int* __restrict__ amax_all, const float* __restrict__ lse_all,
    float* __restrict__ out, double* __restrict__ persample)
{
    int b = blockIdx.x;
    int lane = threadIdx.x;               // 0..63

    __shared__ float  cost[QQ * QQ];      // f32 cost[qp][ql]
    __shared__ double lds_u[QQ];          // u mirror (pre-run values)
    __shared__ float  tagrow[QQ * NE];    // tag_pred[b] staged
    __shared__ int    sl_s[QQ], sl_e[QQ], sl_t[QQ];
    __shared__ float  sps[QQ], spe[QQ];
    __shared__ float  qmax[QQ], qden[QQ];
    __shared__ int    colOfRow[QQ];

    const float4* tp4 = (const float4*)(tag_pred + (size_t)b * QQ * NE);
    float4* tr4 = (float4*)tagrow;
    for (int k = lane; k < 512; k += 64) tr4[k] = tp4[k];
    sl_s[lane] = s_label[b * QQ + lane];
    sl_e[lane] = e_label[b * QQ + lane];
    sl_t[lane] = t_label[b * QQ + lane];
    sps[lane] = (float)amax_all[b * QQ + lane];
    spe[lane] = (float)amax_all[BB * QQ + b * QQ + lane];
    lds_u[lane] = 0.0;
    __syncthreads();

    // per-qp tag softmax stats (f32 max, correctly-rounded exp, sequential sum)
    {
        float mx = tagrow[lane * NE];
        for (int c = 1; c < NE; c++) mx = fmaxf(mx, tagrow[lane * NE + c]);
        float den = 0.f;
        for (int c = 0; c < NE; c++) {
            float d = tagrow[lane * NE + c] - mx;
            float u = (float)exp((double)d);
            den += u;
        }
        qmax[lane] = mx; qden[lane] = den;
    }
    __syncthreads();

    // cost build: lane = ql, loop over qp
    {
        float ls = (float)sl_s[lane], le = (float)sl_e[lane];
        float l_l = fminf(ls, le), l_r = fmaxf(ls, le);
        int   tl = sl_t[lane];
        for (int qp = 0; qp < QQ; qp++) {
            float ps = sps[qp], pe = spe[qp];
            float span = fabsf(ps - ls) + fabsf(pe - le);
            float p_l = fminf(ps, pe), p_r = fmaxf(ps, pe);
            float i_l = fmaxf(p_l, l_l);
            float inter = fmaxf(p_r - i_l, 0.f);   // faithful to reference bug
            float u_l2 = fminf(p_l, l_l), u_r = fmaxf(p_r, l_r);
            float uni = fmaxf(u_r - u_l2, 1e-10f);
            float iou = (-inter) / uni;            // IEEE f32 divide
            float x = tagrow[qp * NE + tl];
            float unn = (float)exp((double)(x - qmax[qp]));
            float cls = -(unn / qden[qp]);
            cost[qp * QQ + lane] = (span + iou) + cls;
        }
    }
    __syncthreads();

    // ---------------- Hungarian (JV), f64, exact replica ----------------
    const double INFV = 1e18;
    const unsigned long long infb = __builtin_bit_cast(unsigned long long, 1e18);
    const unsigned int INFHI_T = (unsigned int)(infb >> 32) | 0x80000000u;

    double v_l = 0.0;     // v[lane+1]
    double u_l = 0.0;     // u[lane+1]  (lane as row)
    int    p_l = 0;       // p[lane+1] = row matched to col lane+1 (0=free)

    for (int i = 1; i <= QQ; i++) {
        int p0 = i;
        int j0 = 0;
        double minv_l = INFV;
        int    way_l = 0;
        bool   used_l = false;
        bool   rowUsed_l = false;
        int r = i - 1;
        // prefetch first row's cost element + pre-run u (lds_u is current:
        // mirror written at the end of the previous run)
        float  cpre = cost[r * QQ + lane];
        double upre = lds_u[r];
        double delta = 0.0;
        for (;;) {
            if (j0 != 0 && lane == j0 - 1) used_l = true;
            if (lane == r) rowUsed_l = true;
            // fused decay: reference's "minv[~used] -= delta" from the END of
            // the previous iteration; minv[j0] (just-marked used) misses one
            // decay — dead value (never read again).
            if (!used_l) minv_l -= delta;

            // --- phase A: transform + mask + reduce over minv_dec.
            // Independent of cur -> overlaps the in-flight ds_read latency.
            unsigned long long ab = __builtin_bit_cast(unsigned long long, minv_l);
            unsigned int abhi = (unsigned int)(ab >> 32);
            unsigned int ablo = (unsigned int)ab;
            unsigned int asm_ = (unsigned int)((int)abhi >> 31);
            unsigned int tahi = abhi ^ (asm_ | 0x80000000u);
            unsigned int talo = ablo ^ asm_;
            unsigned int ahm = used_l ? INFHI_T : tahi;
            unsigned int redA = wave_min_u32(ahm);

            // --- cur (consumes ds data), compare, select ---
            double cur = ((double)cpre - upre) - v_l;
            bool upd = (!used_l) && (cur < minv_l);
            if (upd) { minv_l = cur; way_l = j0; }

            // --- phase B: transform + mask + reduce over cur ---
            unsigned long long bb = __builtin_bit_cast(unsigned long long, cur);
            unsigned int bbhi = (unsigned int)(bb >> 32);
            unsigned int bblo = (unsigned int)bb;
            unsigned int bsm = (unsigned int)((int)bbhi >> 31);
            unsigned int tbhi = bbhi ^ (bsm | 0x80000000u);
            unsigned int tblo = bblo ^ bsm;
            unsigned int bhm = used_l ? INFHI_T : tbhi;
            unsigned int redB = wave_min_u32(bhm);

            // combined hi-min; per-lane key = transform(minv_new) (masked)
            unsigned int mhi = redA < redB ? redA : redB;
            unsigned int keyhi = upd ? bhm : ahm;
            unsigned int keylo = upd ? tblo : talo;
            bool hieq = (keyhi == mhi);
            unsigned long long hmask = __ballot(hieq);
            int l; unsigned int mlo;
            if (__popcll(hmask) == 1) {
                l = __ffsll((long long)hmask) - 1;
                mlo = (unsigned int)__builtin_amdgcn_readlane((int)keylo, l);
            } else {
                // exact lo phase among hi-ties, first-index tie-break
                unsigned int lo2 = hieq ? keylo : 0xFFFFFFFFu;
                mlo = wave_min_u32(lo2);
                unsigned long long mask = __ballot(hieq && (lo2 == mlo));
                l = __ffsll((long long)mask) - 1;
            }
            // decode delta from transformed min (uniform, SALU-friendly)
            unsigned int dsm = ~(unsigned int)((int)mhi >> 31);
            unsigned int dhi = mhi ^ (dsm | 0x80000000u);
            unsigned int dlo = mlo ^ dsm;
            delta = __builtin_bit_cast(double,
                        ((unsigned long long)dhi << 32) | dlo);

            // prefetch next row's cost + pre-run u (row p[j1] not yet in the
            // tree => u[p[j1]] is its pre-run value, present in lds_u)
            int pj1 = __builtin_amdgcn_readlane(p_l, l);
            int rc = (pj1 - 1) & 63;
            float  cnext = cost[rc * QQ + lane];
            double unext = lds_u[rc];

            if (rowUsed_l) u_l += delta;     // u[p[used]] += delta
            if (used_l)   v_l -= delta;      // v[used]   -= delta
            j0 = l + 1;
            if (pj1 == 0) break;
            r = rc; cpre = cnext; upre = unext;
        }
        // mirror u for the next run (u is final once the scan ends;
        // augment below does not modify u)
        lds_u[lane] = u_l;
        // augment along way[] chain
        while (j0 != 0) {
            int j1a = __builtin_amdgcn_readlane(way_l, j0 - 1);
            int pj1 = (j1a == 0) ? p0 : __builtin_amdgcn_readlane(p_l, j1a - 1);
            if (lane == j0 - 1) p_l = pj1;
            j0 = j1a;
        }
    }

    // col_of_row[p[j]-1] = j-1
    colOfRow[p_l - 1] = lane;
    __syncthreads();
    int jq = colOfRow[lane];                       // j[b][lane]
    out[1 + b * QQ + lane] = (float)jq;

    // ---------------- CE at matched targets ----------------
    int ts = sl_s[jq], te = sl_e[jq], tt = sl_t[jq];
    float lses = lse_all[b * QQ + lane];
    float lsee = lse_all[BB * QQ + b * QQ + lane];
    float xs = start_pred[((size_t)(b * QQ + lane)) * LLEN + ts];
    float xe = end_pred[((size_t)(b * QQ + lane)) * LLEN + te];
    float xt = tagrow[lane * NE + tt];
    double ce = ((double)lses - (double)xs)
              + ((double)lsee - (double)xe)
              + ((double)qmax[lane] + log((double)qden[lane]) - (double)xt);
#pragma unroll
    for (int off = 32; off >= 1; off >>= 1) ce += __shfl_xor(ce, off);
    if (lane == 0) persample[b] = ce / 64.0;
}

// ---------------------------------------------------------------------------
// Kernel D: final mean over B -> out[0]
// ---------------------------------------------------------------------------
__global__ __launch_bounds__(64) void final_kernel(
    const double* __restrict__ persample, float* __restrict__ out)
{
    int lane = threadIdx.x;
    double v = persample[lane];
#pragma unroll
    for (int off = 32; off >= 1; off >>= 1) v += __shfl_xor(v, off);
    if (lane == 0) out[0] = (float)(v / 64.0);
}

extern "C" void kernel_launch(void* const* d_in, const int* in_sizes, int n_in,
                              void* d_out, int out_size, void* d_ws, size_t ws_size,
                              hipStream_t stream)
{
    const float* start_pred = (const float*)d_in[0];
    const float* end_pred   = (const float*)d_in[1];
    const float* tag_pred   = (const float*)d_in[2];
    const int*   s_label    = (const int*)d_in[3];
    const int*   e_label    = (const int*)d_in[4];
    const int*   t_label    = (const int*)d_in[5];
    float* out = (float*)d_out;

    // ws layout: amax[8192] int | lse[8192] float | persample[64] double
    int*    amax = (int*)d_ws;
    float*  lse  = (float*)((char*)d_ws + 8192 * sizeof(int));
    double* ps   = (double*)((char*)d_ws + 8192 * sizeof(int) + 8192 * sizeof(float));

    rowstat_kernel<<<2 * BB * QQ, 256, 0, stream>>>(start_pred, end_pred, amax, lse);
    match_kernel<<<BB, QQ, 0, stream>>>(start_pred, end_pred, tag_pred,
                                        s_label, e_label, t_label,
                                        amax, lse, out, ps);
    final_kernel<<<1, QQ, 0, stream>>>(ps, out);
}

// Round 9
// 253.073 us; speedup vs baseline: 1.2572x; 1.2572x over previous
//
#include <hip/hip_runtime.h>
#include <math.h>

// Problem constants (match reference)
#define BB 64
#define QQ 64
#define LLEN 4096
#define NE 32

// ---------------------------------------------------------------------------
// Kernel A: per-row (b,q) argmax (first-max tie-break) and logsumexp over
// L=4096 for start_pred (rows 0..4095) and end_pred (rows 4096..8191).
// ---------------------------------------------------------------------------
__global__ __launch_bounds__(256) void rowstat_kernel(
    const float* __restrict__ sp, const float* __restrict__ ep,
    int* __restrict__ amax, float* __restrict__ lse)
{
    int rid = blockIdx.x;                 // 0..8191
    const float* base = (rid < BB * QQ) ? (sp + (size_t)rid * LLEN)
                                        : (ep + (size_t)(rid - BB * QQ) * LLEN);
    int t = threadIdx.x;
    const float4* b4 = (const float4*)base;
    float4 v[4];
#pragma unroll
    for (int k = 0; k < 4; k++) v[k] = b4[t + k * 256];

    float bm = -INFINITY; int bi = 0x7fffffff;
#pragma unroll
    for (int k = 0; k < 4; k++) {
        float a[4] = { v[k].x, v[k].y, v[k].z, v[k].w };
        int base_i = (t + k * 256) * 4;
#pragma unroll
        for (int c = 0; c < 4; c++) {
            int idx = base_i + c;
            if (a[c] > bm || (a[c] == bm && idx < bi)) { bm = a[c]; bi = idx; }
        }
    }
#pragma unroll
    for (int off = 32; off >= 1; off >>= 1) {
        float om = __shfl_xor(bm, off);
        int   oi = __shfl_xor(bi, off);
        if (om > bm || (om == bm && oi < bi)) { bm = om; bi = oi; }
    }
    __shared__ float smax[4]; __shared__ int sidx[4];
    int wave = t >> 6, lane = t & 63;
    if (lane == 0) { smax[wave] = bm; sidx[wave] = bi; }
    __syncthreads();
    float fm = smax[0]; int fi = sidx[0];
#pragma unroll
    for (int w = 1; w < 4; w++) {
        float om = smax[w]; int oi = sidx[w];
        if (om > fm || (om == fm && oi < fi)) { fm = om; fi = oi; }
    }

    float s = 0.f;
#pragma unroll
    for (int k = 0; k < 4; k++) {
        float a[4] = { v[k].x, v[k].y, v[k].z, v[k].w };
#pragma unroll
        for (int c = 0; c < 4; c++) s += __expf(a[c] - fm);
    }
#pragma unroll
    for (int off = 32; off >= 1; off >>= 1) s += __shfl_xor(s, off);
    __shared__ float ssum[4];
    if (lane == 0) ssum[wave] = s;
    __syncthreads();
    if (t == 0) {
        float tot = ssum[0] + ssum[1] + ssum[2] + ssum[3];
        amax[rid] = fi;
        lse[rid]  = fm + logf(tot);
    }
}

// ---------------------------------------------------------------------------
// Cross-lane helpers
// ---------------------------------------------------------------------------
// wave64 u32 min via DPP (row_shr 1/2/4/8, row_bcast15, row_bcast31);
// full-wave min lands in lane 63. Invalid lanes keep identity 0xFFFFFFFF.
__device__ __forceinline__ unsigned int wave_min_u32(unsigned int x) {
    int xi = (int)x;
#define DPP_MIN_STEP(ctrl)                                                     \
    {                                                                          \
        int yi = __builtin_amdgcn_update_dpp(-1, xi, ctrl, 0xf, 0xf, false);   \
        unsigned int a = (unsigned int)xi, bq = (unsigned int)yi;              \
        xi = (int)(a < bq ? a : bq);                                           \
    }
    DPP_MIN_STEP(0x111)  // row_shr:1
    DPP_MIN_STEP(0x112)  // row_shr:2
    DPP_MIN_STEP(0x114)  // row_shr:4
    DPP_MIN_STEP(0x118)  // row_shr:8
    DPP_MIN_STEP(0x142)  // row_bcast:15
    DPP_MIN_STEP(0x143)  // row_bcast:31
#undef DPP_MIN_STEP
    return (unsigned int)__builtin_amdgcn_readlane(xi, 63);
}

// ---------------------------------------------------------------------------
// Kernel C: cost build (f32, bit-matching JAX f32 ops) into LDS; Hungarian
// (JV) in f64, operation-for-operation replica of the numpy reference (full
// row loop — REQUIRED: optimum non-unique, output path-dependent).
// R8 = R6 single-reduction structure (R7's split-reduce regressed: two
// serial 6-DPP chains, no overlap on a lone wave) + two cuts:
//  (a) merged tie-path: l = ffs(hi-tie mask); mlo = tilo[l]; one ballot
//      verifies no hi-tied lane has smaller lo (covers unique AND exact-
//      duplicate ties — the common case here); full lo-reduction only on the
//      rare hi-tie-with-differing-lo. Exact first-index argmin.
//  (b) u mirrored in LDS, written once per run (rows enter the tree with
//      their PRE-RUN u), prefetched via uniform ds_read with the cost row.
// One block = one sample = 1 wave.
// ---------------------------------------------------------------------------
__global__ __launch_bounds__(64) void match_kernel(
    const float* __restrict__ start_pred, const float* __restrict__ end_pred,
    const float* __restrict__ tag_pred,
    const int* __restrict__ s_label, const int* __restrict__ e_label,
    const int* __restrict__ t_label,
    const int* __restrict__ amax_all, const float* __restrict__ lse_all,
    float* __restrict__ out, double* __restrict__ persample)
{
    int b = blockIdx.x;
    int lane = threadIdx.x;               // 0..63

    __shared__ float  cost[QQ * QQ];      // f32 cost[qp][ql]
    __shared__ double lds_u[QQ];          // u mirror (pre-run values)
    __shared__ float  tagrow[QQ * NE];    // tag_pred[b] staged
    __shared__ int    sl_s[QQ], sl_e[QQ], sl_t[QQ];
    __shared__ float  sps[QQ], spe[QQ];
    __shared__ float  qmax[QQ], qden[QQ];
    __shared__ int    colOfRow[QQ];

    const float4* tp4 = (const float4*)(tag_pred + (size_t)b * QQ * NE);
    float4* tr4 = (float4*)tagrow;
    for (int k = lane; k < 512; k += 64) tr4[k] = tp4[k];
    sl_s[lane] = s_label[b * QQ + lane];
    sl_e[lane] = e_label[b * QQ + lane];
    sl_t[lane] = t_label[b * QQ + lane];
    sps[lane] = (float)amax_all[b * QQ + lane];
    spe[lane] = (float)amax_all[BB * QQ + b * QQ + lane];
    lds_u[lane] = 0.0;
    __syncthreads();

    // per-qp tag softmax stats (f32 max, correctly-rounded exp, sequential sum)
    {
        float mx = tagrow[lane * NE];
        for (int c = 1; c < NE; c++) mx = fmaxf(mx, tagrow[lane * NE + c]);
        float den = 0.f;
        for (int c = 0; c < NE; c++) {
            float d = tagrow[lane * NE + c] - mx;
            float u = (float)exp((double)d);
            den += u;
        }
        qmax[lane] = mx; qden[lane] = den;
    }
    __syncthreads();

    // cost build: lane = ql, loop over qp
    {
        float ls = (float)sl_s[lane], le = (float)sl_e[lane];
        float l_l = fminf(ls, le), l_r = fmaxf(ls, le);
        int   tl = sl_t[lane];
        for (int qp = 0; qp < QQ; qp++) {
            float ps = sps[qp], pe = spe[qp];
            float span = fabsf(ps - ls) + fabsf(pe - le);
            float p_l = fminf(ps, pe), p_r = fmaxf(ps, pe);
            float i_l = fmaxf(p_l, l_l);
            float inter = fmaxf(p_r - i_l, 0.f);   // faithful to reference bug
            float u_l2 = fminf(p_l, l_l), u_r = fmaxf(p_r, l_r);
            float uni = fmaxf(u_r - u_l2, 1e-10f);
            float iou = (-inter) / uni;            // IEEE f32 divide
            float x = tagrow[qp * NE + tl];
            float unn = (float)exp((double)(x - qmax[qp]));
            float cls = -(unn / qden[qp]);
            cost[qp * QQ + lane] = (span + iou) + cls;
        }
    }
    __syncthreads();

    // ---------------- Hungarian (JV), f64, exact replica ----------------
    const double INFV = 1e18;
    const unsigned long long infb = __builtin_bit_cast(unsigned long long, 1e18);
    const unsigned int INFHI_T = (unsigned int)(infb >> 32) | 0x80000000u;

    double v_l = 0.0;     // v[lane+1]
    double u_l = 0.0;     // u[lane+1]  (lane as row)
    int    p_l = 0;       // p[lane+1] = row matched to col lane+1 (0=free)

    for (int i = 1; i <= QQ; i++) {
        int p0 = i;
        int j0 = 0;
        double minv_l = INFV;
        int    way_l = 0;
        bool   used_l = false;
        bool   rowUsed_l = false;
        int r = i - 1;
        // prefetch first row's cost element + pre-run u
        float  cpre = cost[r * QQ + lane];
        double upre = lds_u[r];
        double delta = 0.0;
        for (;;) {
            if (j0 != 0 && lane == j0 - 1) used_l = true;
            if (lane == r) rowUsed_l = true;
            // fused decay: reference's "minv[~used] -= delta" from the END of
            // the previous iteration; minv[j0] (just-marked used) misses one
            // decay — dead value (never read again).
            if (!used_l) minv_l -= delta;
            double cur = ((double)cpre - upre) - v_l;
            if (!used_l && cur < minv_l) { minv_l = cur; way_l = j0; }

            // exact argmin (value, first-index) on f64 keys: monotone
            // double->u64 transform (no -0.0 arises), hi-32 DPP min.
            unsigned long long kb = __builtin_bit_cast(unsigned long long, minv_l);
            unsigned int kbhi = (unsigned int)(kb >> 32);
            unsigned int kblo = (unsigned int)kb;
            unsigned int sm = (unsigned int)((int)kbhi >> 31);
            unsigned int tihi = kbhi ^ (sm | 0x80000000u);
            unsigned int tilo = kblo ^ sm;
            unsigned int keyhi = used_l ? INFHI_T : tihi;
            unsigned int mhi = wave_min_u32(keyhi);
            bool hieq = (keyhi == mhi);
            unsigned long long hmask = __ballot(hieq);
            // merged tie-path: first hi-tied lane; verify it attains min lo.
            // Covers unique-hi AND exact-duplicate ties (equal lo) in one
            // path; full lo-reduction only if a later lane has smaller lo.
            int l = __ffsll((long long)hmask) - 1;
            unsigned int mlo = (unsigned int)__builtin_amdgcn_readlane((int)tilo, l);
            unsigned long long bad = __ballot(hieq && (tilo < mlo));
            if (bad) {
                unsigned int lo2 = hieq ? tilo : 0xFFFFFFFFu;
                mlo = wave_min_u32(lo2);
                unsigned long long mask = __ballot(hieq && (lo2 == mlo));
                l = __ffsll((long long)mask) - 1;
            }
            // decode delta from transformed min (uniform, SALU-friendly)
            unsigned int dsm = ~(unsigned int)((int)mhi >> 31);
            unsigned int dhi = mhi ^ (dsm | 0x80000000u);
            unsigned int dlo = mlo ^ dsm;
            delta = __builtin_bit_cast(double,
                        ((unsigned long long)dhi << 32) | dlo);

            // prefetch + precompute next scan inputs BEFORE dual updates:
            // row p[j1] is not yet in the tree (u at pre-run value, in lds_u);
            // v_l static for free columns; used columns' cur is masked.
            int pj1 = __builtin_amdgcn_readlane(p_l, l);
            int rc = (pj1 - 1) & 63;
            float  cnext = cost[rc * QQ + lane];
            double unext = lds_u[rc];

            if (rowUsed_l) u_l += delta;     // u[p[used]] += delta
            if (used_l)   v_l -= delta;      // v[used]   -= delta
            j0 = l + 1;
            if (pj1 == 0) break;
            r = rc; cpre = cnext; upre = unext;
        }
        // mirror u for the next run (u is final once the scan ends)
        lds_u[lane] = u_l;
        // augment along way[] chain
        while (j0 != 0) {
            int j1a = __builtin_amdgcn_readlane(way_l, j0 - 1);
            int pj1 = (j1a == 0) ? p0 : __builtin_amdgcn_readlane(p_l, j1a - 1);
            if (lane == j0 - 1) p_l = pj1;
            j0 = j1a;
        }
    }

    // col_of_row[p[j]-1] = j-1
    colOfRow[p_l - 1] = lane;
    __syncthreads();
    int jq = colOfRow[lane];                       // j[b][lane]
    out[1 + b * QQ + lane] = (float)jq;

    // ---------------- CE at matched targets ----------------
    int ts = sl_s[jq], te = sl_e[jq], tt = sl_t[jq];
    float lses = lse_all[b * QQ + lane];
    float lsee = lse_all[BB * QQ + b * QQ + lane];
    float xs = start_pred[((size_t)(b * QQ + lane)) * LLEN + ts];
    float xe = end_pred[((size_t)(b * QQ + lane)) * LLEN + te];
    float xt = tagrow[lane * NE + tt];
    double ce = ((double)lses - (double)xs)
              + ((double)lsee - (double)xe)
              + ((double)qmax[lane] + log((double)qden[lane]) - (double)xt);
#pragma unroll
    for (int off = 32; off >= 1; off >>= 1) ce += __shfl_xor(ce, off);
    if (lane == 0) persample[b] = ce / 64.0;
}

// ---------------------------------------------------------------------------
// Kernel D: final mean over B -> out[0]
// ---------------------------------------------------------------------------
__global__ __launch_bounds__(64) void final_kernel(
    const double* __restrict__ persample, float* __restrict__ out)
{
    int lane = threadIdx.x;
    double v = persample[lane];
#pragma unroll
    for (int off = 32; off >= 1; off >>= 1) v += __shfl_xor(v, off);
    if (lane == 0) out[0] = (float)(v / 64.0);
}

extern "C" void kernel_launch(void* const* d_in, const int* in_sizes, int n_in,
                              void* d_out, int out_size, void* d_ws, size_t ws_size,
                              hipStream_t stream)
{
    const float* start_pred = (const float*)d_in[0];
    const float* end_pred   = (const float*)d_in[1];
    const float* tag_pred   = (const float*)d_in[2];
    const int*   s_label    = (const int*)d_in[3];
    const int*   e_label    = (const int*)d_in[4];
    const int*   t_label    = (const int*)d_in[5];
    float* out = (float*)d_out;

    // ws layout: amax[8192] int | lse[8192] float | persample[64] double
    int*    amax = (int*)d_ws;
    float*  lse  = (float*)((char*)d_ws + 8192 * sizeof(int));
    double* ps   = (double*)((char*)d_ws + 8192 * sizeof(int) + 8192 * sizeof(float));

    rowstat_kernel<<<2 * BB * QQ, 256, 0, stream>>>(start_pred, end_pred, amax, lse);
    match_kernel<<<BB, QQ, 0, stream>>>(start_pred, end_pred, tag_pred,
                                        s_label, e_label, t_label,
                                        amax, lse, out, ps);
    final_kernel<<<1, QQ, 0, stream>>>(ps, out);
}

// Round 10
// 251.133 us; speedup vs baseline: 1.2669x; 1.0077x over previous
//
#include <hip/hip_runtime.h>
#include <math.h>

// Problem constants (match reference)
#define BB 64
#define QQ 64
#define LLEN 4096
#define NE 32

// ---------------------------------------------------------------------------
// Kernel A: per-row (b,q) argmax (first-max tie-break) and logsumexp over
// L=4096 for start_pred (rows 0..4095) and end_pred (rows 4096..8191).
// ---------------------------------------------------------------------------
__global__ __launch_bounds__(256) void rowstat_kernel(
    const float* __restrict__ sp, const float* __restrict__ ep,
    int* __restrict__ amax, float* __restrict__ lse)
{
    int rid = blockIdx.x;                 // 0..8191
    const float* base = (rid < BB * QQ) ? (sp + (size_t)rid * LLEN)
                                        : (ep + (size_t)(rid - BB * QQ) * LLEN);
    int t = threadIdx.x;
    const float4* b4 = (const float4*)base;
    float4 v[4];
#pragma unroll
    for (int k = 0; k < 4; k++) v[k] = b4[t + k * 256];

    float bm = -INFINITY; int bi = 0x7fffffff;
#pragma unroll
    for (int k = 0; k < 4; k++) {
        float a[4] = { v[k].x, v[k].y, v[k].z, v[k].w };
        int base_i = (t + k * 256) * 4;
#pragma unroll
        for (int c = 0; c < 4; c++) {
            int idx = base_i + c;
            if (a[c] > bm || (a[c] == bm && idx < bi)) { bm = a[c]; bi = idx; }
        }
    }
#pragma unroll
    for (int off = 32; off >= 1; off >>= 1) {
        float om = __shfl_xor(bm, off);
        int   oi = __shfl_xor(bi, off);
        if (om > bm || (om == bm && oi < bi)) { bm = om; bi = oi; }
    }
    __shared__ float smax[4]; __shared__ int sidx[4];
    int wave = t >> 6, lane = t & 63;
    if (lane == 0) { smax[wave] = bm; sidx[wave] = bi; }
    __syncthreads();
    float fm = smax[0]; int fi = sidx[0];
#pragma unroll
    for (int w = 1; w < 4; w++) {
        float om = smax[w]; int oi = sidx[w];
        if (om > fm || (om == fm && oi < fi)) { fm = om; fi = oi; }
    }

    float s = 0.f;
#pragma unroll
    for (int k = 0; k < 4; k++) {
        float a[4] = { v[k].x, v[k].y, v[k].z, v[k].w };
#pragma unroll
        for (int c = 0; c < 4; c++) s += __expf(a[c] - fm);
    }
#pragma unroll
    for (int off = 32; off >= 1; off >>= 1) s += __shfl_xor(s, off);
    __shared__ float ssum[4];
    if (lane == 0) ssum[wave] = s;
    __syncthreads();
    if (t == 0) {
        float tot = ssum[0] + ssum[1] + ssum[2] + ssum[3];
        amax[rid] = fi;
        lse[rid]  = fm + logf(tot);
    }
}

// ---------------------------------------------------------------------------
// Cross-lane helpers
// ---------------------------------------------------------------------------
__device__ __forceinline__ double readlane_f64(double x, int l) {
    union { double d; int i[2]; } u; u.d = x;
    int lo = __builtin_amdgcn_readlane(u.i[0], l);
    int hi = __builtin_amdgcn_readlane(u.i[1], l);
    union { int i[2]; double d; } r; r.i[0] = lo; r.i[1] = hi;
    return r.d;
}

// wave64 u32 min via DPP (row_shr 1/2/4/8, row_bcast15, row_bcast31);
// full-wave min lands in lane 63. Invalid lanes keep identity 0xFFFFFFFF.
__device__ __forceinline__ unsigned int wave_min_u32(unsigned int x) {
    int xi = (int)x;
#define DPP_MIN_STEP(ctrl)                                                     \
    {                                                                          \
        int yi = __builtin_amdgcn_update_dpp(-1, xi, ctrl, 0xf, 0xf, false);   \
        unsigned int a = (unsigned int)xi, bq = (unsigned int)yi;              \
        xi = (int)(a < bq ? a : bq);                                           \
    }
    DPP_MIN_STEP(0x111)  // row_shr:1
    DPP_MIN_STEP(0x112)  // row_shr:2
    DPP_MIN_STEP(0x114)  // row_shr:4
    DPP_MIN_STEP(0x118)  // row_shr:8
    DPP_MIN_STEP(0x142)  // row_bcast:15
    DPP_MIN_STEP(0x143)  // row_bcast:31
#undef DPP_MIN_STEP
    return (unsigned int)__builtin_amdgcn_readlane(xi, 63);
}

// ---------------------------------------------------------------------------
// Kernel C: cost build (f32, bit-matching JAX f32 ops) into LDS; Hungarian
// (JV) in f64, operation-for-operation replica of the numpy reference (full
// row loop — REQUIRED: optimum non-unique, output path-dependent).
// R9 = R8 + (1) delta read directly as f64 from the argmin lane (reference's
// delta = minv[j1]; replaces the SALU bit-untransform, available ~15cy
// earlier) + (2) optimistic prefetch issue with the fast-path lane BEFORE the
// bad-check ballot; rare bad case recomputes and re-issues.
// One block = one sample = 1 wave.
// ---------------------------------------------------------------------------
__global__ __launch_bounds__(64) void match_kernel(
    const float* __restrict__ start_pred, const float* __restrict__ end_pred,
    const float* __restrict__ tag_pred,
    const int* __restrict__ s_label, const int* __restrict__ e_label,
    const int* __restrict__ t_label,
    const int* __restrict__ amax_all, const float* __restrict__ lse_all,
    float* __restrict__ out, double* __restrict__ persample)
{
    int b = blockIdx.x;
    int lane = threadIdx.x;               // 0..63

    __shared__ float  cost[QQ * QQ];      // f32 cost[qp][ql]
    __shared__ double lds_u[QQ];          // u mirror (pre-run values)
    __shared__ float  tagrow[QQ * NE];    // tag_pred[b] staged
    __shared__ int    sl_s[QQ], sl_e[QQ], sl_t[QQ];
    __shared__ float  sps[QQ], spe[QQ];
    __shared__ float  qmax[QQ], qden[QQ];
    __shared__ int    colOfRow[QQ];

    const float4* tp4 = (const float4*)(tag_pred + (size_t)b * QQ * NE);
    float4* tr4 = (float4*)tagrow;
    for (int k = lane; k < 512; k += 64) tr4[k] = tp4[k];
    sl_s[lane] = s_label[b * QQ + lane];
    sl_e[lane] = e_label[b * QQ + lane];
    sl_t[lane] = t_label[b * QQ + lane];
    sps[lane] = (float)amax_all[b * QQ + lane];
    spe[lane] = (float)amax_all[BB * QQ + b * QQ + lane];
    lds_u[lane] = 0.0;
    __syncthreads();

    // per-qp tag softmax stats (f32 max, correctly-rounded exp, sequential sum)
    {
        float mx = tagrow[lane * NE];
        for (int c = 1; c < NE; c++) mx = fmaxf(mx, tagrow[lane * NE + c]);
        float den = 0.f;
        for (int c = 0; c < NE; c++) {
            float d = tagrow[lane * NE + c] - mx;
            float u = (float)exp((double)d);
            den += u;
        }
        qmax[lane] = mx; qden[lane] = den;
    }
    __syncthreads();

    // cost build: lane = ql, loop over qp
    {
        float ls = (float)sl_s[lane], le = (float)sl_e[lane];
        float l_l = fminf(ls, le), l_r = fmaxf(ls, le);
        int   tl = sl_t[lane];
        for (int qp = 0; qp < QQ; qp++) {
            float ps = sps[qp], pe = spe[qp];
            float span = fabsf(ps - ls) + fabsf(pe - le);
            float p_l = fminf(ps, pe), p_r = fmaxf(ps, pe);
            float i_l = fmaxf(p_l, l_l);
            float inter = fmaxf(p_r - i_l, 0.f);   // faithful to reference bug
            float u_l2 = fminf(p_l, l_l), u_r = fmaxf(p_r, l_r);
            float uni = fmaxf(u_r - u_l2, 1e-10f);
            float iou = (-inter) / uni;            // IEEE f32 divide
            float x = tagrow[qp * NE + tl];
            float unn = (float)exp((double)(x - qmax[qp]));
            float cls = -(unn / qden[qp]);
            cost[qp * QQ + lane] = (span + iou) + cls;
        }
    }
    __syncthreads();

    // ---------------- Hungarian (JV), f64, exact replica ----------------
    const double INFV = 1e18;
    const unsigned long long infb = __builtin_bit_cast(unsigned long long, 1e18);
    const unsigned int INFHI_T = (unsigned int)(infb >> 32) | 0x80000000u;

    double v_l = 0.0;     // v[lane+1]
    double u_l = 0.0;     // u[lane+1]  (lane as row)
    int    p_l = 0;       // p[lane+1] = row matched to col lane+1 (0=free)

    for (int i = 1; i <= QQ; i++) {
        int p0 = i;
        int j0 = 0;
        double minv_l = INFV;
        int    way_l = 0;
        bool   used_l = false;
        bool   rowUsed_l = false;
        int r = i - 1;
        // prefetch first row's cost element + pre-run u
        float  cpre = cost[r * QQ + lane];
        double upre = lds_u[r];
        double delta = 0.0;
        for (;;) {
            if (j0 != 0 && lane == j0 - 1) used_l = true;
            if (lane == r) rowUsed_l = true;
            // fused decay: reference's "minv[~used] -= delta" from the END of
            // the previous iteration; minv[j0] (just-marked used) misses one
            // decay — dead value (never read again).
            if (!used_l) minv_l -= delta;
            double cur = ((double)cpre - upre) - v_l;
            if (!used_l && cur < minv_l) { minv_l = cur; way_l = j0; }

            // exact argmin (value, first-index) on f64 keys: monotone
            // double->u64 transform (no -0.0 arises), hi-32 DPP min.
            unsigned long long kb = __builtin_bit_cast(unsigned long long, minv_l);
            unsigned int kbhi = (unsigned int)(kb >> 32);
            unsigned int kblo = (unsigned int)kb;
            unsigned int sm = (unsigned int)((int)kbhi >> 31);
            unsigned int tihi = kbhi ^ (sm | 0x80000000u);
            unsigned int tilo = kblo ^ sm;
            unsigned int keyhi = used_l ? INFHI_T : tihi;
            unsigned int mhi = wave_min_u32(keyhi);
            bool hieq = (keyhi == mhi);
            unsigned long long hmask = __ballot(hieq);
            // merged tie-path: first hi-tied lane; optimistic prefetch with
            // it; one ballot verifies it attains min lo (covers unique-hi AND
            // exact-duplicate ties). Rare differing-lo case recomputes.
            int l = __ffsll((long long)hmask) - 1;
            // optimistic prefetch issue (re-done in the rare bad case)
            int pj1 = __builtin_amdgcn_readlane(p_l, l);
            int rc = (pj1 - 1) & 63;
            float  cnext = cost[rc * QQ + lane];
            double unext = lds_u[rc];
            unsigned int mlo = (unsigned int)__builtin_amdgcn_readlane((int)tilo, l);
            unsigned long long bad = __ballot(hieq && (tilo < mlo));
            if (bad) {
                unsigned int lo2 = hieq ? tilo : 0xFFFFFFFFu;
                mlo = wave_min_u32(lo2);
                unsigned long long mask = __ballot(hieq && (lo2 == mlo));
                l = __ffsll((long long)mask) - 1;
                pj1 = __builtin_amdgcn_readlane(p_l, l);
                rc = (pj1 - 1) & 63;
                cnext = cost[rc * QQ + lane];
                unext = lds_u[rc];
            }
            // delta = minv[j1] read directly as f64 from the argmin lane
            // (identical to the reference's delta; no SALU untransform)
            delta = readlane_f64(minv_l, l);

            if (rowUsed_l) u_l += delta;     // u[p[used]] += delta
            if (used_l)   v_l -= delta;      // v[used]   -= delta
            j0 = l + 1;
            if (pj1 == 0) break;
            r = rc; cpre = cnext; upre = unext;
        }
        // mirror u for the next run (u is final once the scan ends)
        lds_u[lane] = u_l;
        // augment along way[] chain
        while (j0 != 0) {
            int j1a = __builtin_amdgcn_readlane(way_l, j0 - 1);
            int pj1 = (j1a == 0) ? p0 : __builtin_amdgcn_readlane(p_l, j1a - 1);
            if (lane == j0 - 1) p_l = pj1;
            j0 = j1a;
        }
    }

    // col_of_row[p[j]-1] = j-1
    colOfRow[p_l - 1] = lane;
    __syncthreads();
    int jq = colOfRow[lane];                       // j[b][lane]
    out[1 + b * QQ + lane] = (float)jq;

    // ---------------- CE at matched targets ----------------
    int ts = sl_s[jq], te = sl_e[jq], tt = sl_t[jq];
    float lses = lse_all[b * QQ + lane];
    float lsee = lse_all[BB * QQ + b * QQ + lane];
    float xs = start_pred[((size_t)(b * QQ + lane)) * LLEN + ts];
    float xe = end_pred[((size_t)(b * QQ + lane)) * LLEN + te];
    float xt = tagrow[lane * NE + tt];
    double ce = ((double)lses - (double)xs)
              + ((double)lsee - (double)xe)
              + ((double)qmax[lane] + log((double)qden[lane]) - (double)xt);
#pragma unroll
    for (int off = 32; off >= 1; off >>= 1) ce += __shfl_xor(ce, off);
    if (lane == 0) persample[b] = ce / 64.0;
}

// ---------------------------------------------------------------------------
// Kernel D: final mean over B -> out[0]
// ---------------------------------------------------------------------------
__global__ __launch_bounds__(64) void final_kernel(
    const double* __restrict__ persample, float* __restrict__ out)
{
    int lane = threadIdx.x;
    double v = persample[lane];
#pragma unroll
    for (int off = 32; off >= 1; off >>= 1) v += __shfl_xor(v, off);
    if (lane == 0) out[0] = (float)(v / 64.0);
}

extern "C" void kernel_launch(void* const* d_in, const int* in_sizes, int n_in,
                              void* d_out, int out_size, void* d_ws, size_t ws_size,
                              hipStream_t stream)
{
    const float* start_pred = (const float*)d_in[0];
    const float* end_pred   = (const float*)d_in[1];
    const float* tag_pred   = (const float*)d_in[2];
    const int*   s_label    = (const int*)d_in[3];
    const int*   e_label    = (const int*)d_in[4];
    const int*   t_label    = (const int*)d_in[5];
    float* out = (float*)d_out;

    // ws layout: amax[8192] int | lse[8192] float | persample[64] double
    int*    amax = (int*)d_ws;
    float*  lse  = (float*)((char*)d_ws + 8192 * sizeof(int));
    double* ps   = (double*)((char*)d_ws + 8192 * sizeof(int) + 8192 * sizeof(float));

    rowstat_kernel<<<2 * BB * QQ, 256, 0, stream>>>(start_pred, end_pred, amax, lse);
    match_kernel<<<BB, QQ, 0, stream>>>(start_pred, end_pred, tag_pred,
                                        s_label, e_label, t_label,
                                        amax, lse, out, ps);
    final_kernel<<<1, QQ, 0, stream>>>(ps, out);
}